// Round 17
// baseline (4060.384 us; speedup 1.0000x reference)
//
#include <hip/hip_runtime.h>
#include <math.h>
#include <stdint.h>

typedef float f32x4 __attribute__((ext_vector_type(4)));

__device__ __forceinline__ float sigm(float x) { return 1.0f/(1.0f+expf(-x)); }

// Sum across each 8-lane group via DIRECTION-PROOF DPP involutions:
// quad_perm xor1 (0xB1), quad_perm xor2 (0x4E) -> every lane holds its quad
// sum; row_half_mirror (0x141: i <-> 7-i within each 8-group) adds the other
// quad's sum. ALL 8 lanes end with the full 8-group sum. Round-16 lesson:
// row_ror over a SUB-group is rotation-direction-sensitive (red16 over the
// full row masked this); ror pulled 7/8 values from the neighboring group ->
// absmax 3.7e-3. XOR/mirror patterns are self-inverse -> no direction
// assumption.
__device__ __forceinline__ float red8(float v) {
    int t;
    t = __builtin_amdgcn_update_dpp(0, __float_as_int(v), 0xB1, 0xf, 0xf, false);
    v += __int_as_float(t);   // + lane^1 (quad_perm [1,0,3,2])
    t = __builtin_amdgcn_update_dpp(0, __float_as_int(v), 0x4E, 0xf, 0xf, false);
    v += __int_as_float(t);   // + lane^2 (quad_perm [2,3,0,1]) -> quad sums
    t = __builtin_amdgcn_update_dpp(0, __float_as_int(v), 0x141, 0xf, 0xf, false);
    v += __int_as_float(t);   // + mirrored lane (7-i in 8-group) -> 8-sum
    return v;
}

// ------------- Kernel 1: LSTM recurrence, all-direct K-split waves -------------
// Round-15 structure (PASSED 2.67ms, VALUBusy 75% = VALU-issue-bound) with the
// 8 ksegs x 8 rows lane remap (round 16) and the FIXED direction-proof red8.
// Per lane per phase: 16 K-floats (4 f32x4-FMA x 2 batch = 8 useful instrs)
// vs epilogue 6 horiz + 2x red8(3 DPP) -- ~55% useful (was 22% at 16x4).
// Phases halve to 16 (64 gate-rows each). Same bytes, same coalescing
// (8x128B segments/instr). 2-deep pipeline (round-13 null: depth>2 no help;
// TLP at 4 waves/SIMD hides L2). ~95 VGPR < 128 cap (rounds 7-10 lesson).
// 256 blocks x 1024 threads, 2 batch rows/block; wave half = K-half.
// Partials combined in part[2][2][1024]; pointwise adds halves.
// 2 lgkm-only barriers/step. Reference semantics: cell_state c0 CONSTANT
// (enc[:,-1,:]); scan carry h_{t+1} = c_new_t.
__global__ __launch_bounds__(1024) void rec_kernel(
    const float* __restrict__ enc,   // (512, 64, 256)
    const float* __restrict__ b_ih,  // (1024)
    const float* __restrict__ W_hh,  // (1024, 256)
    const float* __restrict__ b_hh,  // (1024)
    float* __restrict__ hstage)      // (512, 256, 256) staging (= d_out)
{
    const int tid  = threadIdx.x;
    const int wv   = tid >> 6;          // wave 0..15
    const int lane = tid & 63;
    const int kseg = lane & 7;          // 8 K-segments of 16 floats
    const int r8   = lane >> 3;         // 0..7: row within wave's group
    const int half = wv >> 3;           // K-half: 0 -> floats 0..127; 1 -> 128..255
    const int wg   = wv & 7;            // row group
    const int rloc = 8*wg + r8;         // row-in-phase (0..63) this lane computes
    const int b0   = blockIdx.x * 2;

    __shared__ float part[2][2][1024];  // [half][batch][gate-row] 16KB
    __shared__ float h_lds[2][256];     // 2KB

    // ---- pointwise identity: threads 0..511 = (pj, ph) ----
    const int pj = tid & 255;
    const int ph = (tid >> 8) & 1;
    float c0 = 0.f, pb0 = 0.f, pb1 = 0.f, pb2 = 0.f, pb3 = 0.f;
    float* __restrict__ outp = nullptr;
    if (tid < 512) {
        c0  = enc[(size_t)(b0 + ph)*16384 + 16128 + pj];
        pb0 = b_ih[      pj] + b_hh[      pj];
        pb1 = b_ih[256 + pj] + b_hh[256 + pj];
        pb2 = b_ih[512 + pj] + b_hh[512 + pj];
        pb3 = b_ih[768 + pj] + b_hh[768 + pj];
        outp = hstage + (size_t)(b0 + ph)*65536 + pj;
    }

    // per-lane W base: 16 consecutive floats of row rloc, this half
    // phase pm lives at + pm*64rows*256 = pm*16384 floats
    const float* __restrict__ wbase =
        W_hh + (size_t)rloc*256 + half*128 + kseg*16;

    #define LOADP(q0, q1, q2, q3, pm) do {                           \
        const float* wp_ = wbase + (size_t)(pm)*16384;               \
        q0 = *(const f32x4*)(wp_     );                              \
        q1 = *(const f32x4*)(wp_ +  4);                              \
        q2 = *(const f32x4*)(wp_ +  8);                              \
        q3 = *(const f32x4*)(wp_ + 12);                              \
    } while (0)

    #define COMPUTE(q0, q1, q2, q3, p) do {                          \
        f32x4 s0 = q0*h00; f32x4 s1 = q0*h10;                        \
        s0 += q1*h01;      s1 += q1*h11;                             \
        s0 += q2*h02;      s1 += q2*h12;                             \
        s0 += q3*h03;      s1 += q3*h13;                             \
        float a0 = (s0.x + s0.y) + (s0.z + s0.w);                    \
        float a1 = (s1.x + s1.y) + (s1.z + s1.w);                    \
        a0 = red8(a0); a1 = red8(a1);                                \
        if (kseg == 0) {                                             \
            const int grow_ = (p)*64 + rloc;                         \
            part[half][0][grow_] = a0;                               \
            part[half][1][grow_] = a1;                               \
        }                                                            \
    } while (0)

    // h windows: 16 floats per batch row (this lane's kseg), 32 VGPR
    f32x4 h00 = (f32x4)(0.f), h01 = (f32x4)(0.f),
          h02 = (f32x4)(0.f), h03 = (f32x4)(0.f);
    f32x4 h10 = (f32x4)(0.f), h11 = (f32x4)(0.f),
          h12 = (f32x4)(0.f), h13 = (f32x4)(0.f);

    f32x4 wA0, wA1, wA2, wA3, wB0, wB1, wB2, wB3;   // 2-deep pipeline (32 VGPR)

    // prologue: prime phases 0,1 (8 loads/wave in flight)
    LOADP(wA0, wA1, wA2, wA3, 0);
    LOADP(wB0, wB1, wB2, wB3, 1);

    for (int t = 0; t < 256; ++t) {
        #pragma unroll 1
        for (int pq = 0; pq < 8; ++pq) {
            const int p = pq*2;
            COMPUTE(wA0, wA1, wA2, wA3, p    );
            LOADP(wA0, wA1, wA2, wA3, (p + 2) & 15);
            COMPUTE(wB0, wB1, wB2, wB3, p + 1);
            LOADP(wB0, wB1, wB2, wB3, (p + 3) & 15);
        }   // (p+2/p+3 wrap to next step's phases: W identical every step)
        asm volatile("s_waitcnt lgkmcnt(0)" ::: "memory");
        __builtin_amdgcn_s_barrier();           // (1) all partials visible

        // ---- pointwise LSTM: threads 0..511, batch b0+ph, column pj ----
        if (tid < 512) {
            const float g0 = part[0][ph][      pj] + part[1][ph][      pj] + pb0;
            const float g1 = part[0][ph][256 + pj] + part[1][ph][256 + pj] + pb1;
            const float g2 = part[0][ph][512 + pj] + part[1][ph][512 + pj] + pb2;
            const float g3 = part[0][ph][768 + pj] + part[1][ph][768 + pj] + pb3;
            const float cn = sigm(g1)*c0 + sigm(g0)*tanhf(g2);
            const float hn = sigm(g3)*tanhf(cn);
            h_lds[ph][pj] = cn;                 // carry h_{t+1} = c_new
            __builtin_nontemporal_store(hn, outp + t*256);
        }
        asm volatile("s_waitcnt lgkmcnt(0)" ::: "memory");
        __builtin_amdgcn_s_barrier();           // (2) h ready

        // reload this wave's h window (16 floats/batch; 8-addr broadcast,
        // ~4-way bank alias on 8 instrs/step -> negligible)
        h00 = *(const f32x4*)&h_lds[0][half*128 + kseg*16     ];
        h01 = *(const f32x4*)&h_lds[0][half*128 + kseg*16 +  4];
        h02 = *(const f32x4*)&h_lds[0][half*128 + kseg*16 +  8];
        h03 = *(const f32x4*)&h_lds[0][half*128 + kseg*16 + 12];
        h10 = *(const f32x4*)&h_lds[1][half*128 + kseg*16     ];
        h11 = *(const f32x4*)&h_lds[1][half*128 + kseg*16 +  4];
        h12 = *(const f32x4*)&h_lds[1][half*128 + kseg*16 +  8];
        h13 = *(const f32x4*)&h_lds[1][half*128 + kseg*16 + 12];
    }
    #undef LOADP
    #undef COMPUTE
}

// ---------------- Kernel 2: logits + softmax, in place ----------------
// (unchanged — verified correct, ~106 us)
__global__ __launch_bounds__(1024) void out_kernel(
    const float* __restrict__ W2,    // (256, 256)
    const float* __restrict__ b2,    // (256)
    float* __restrict__ io)          // (131072, 256) h in, probs out
{
    const int tid = threadIdx.x;
    const int rg  = tid & 15;
    const int cg  = tid >> 4;        // 0..63
    const int m0  = blockIdx.x * 64;

    __shared__ float tile[64][260];

    #pragma unroll
    for (int i = 0; i < 4; ++i) {
        const int idx = tid + i*1024;     // 0..4095 float4 slots
        const int r   = idx >> 6;
        const int c4  = idx & 63;
        const f32x4 v = __builtin_nontemporal_load(
            (const f32x4*)(io + (size_t)(m0 + r)*256 + c4*4));
        *(f32x4*)&tile[r][c4*4] = v;
    }
    __syncthreads();

    float b2v[4];
    #pragma unroll
    for (int ci = 0; ci < 4; ++ci) b2v[ci] = b2[cg*4 + ci];

    float acc[4][4] = {};

    #pragma unroll 4
    for (int k4 = 0; k4 < 64; ++k4) {
        const f32x4 h0 = *(const f32x4*)&tile[rg     ][k4*4];
        const f32x4 h1 = *(const f32x4*)&tile[rg + 16][k4*4];
        const f32x4 h2 = *(const f32x4*)&tile[rg + 32][k4*4];
        const f32x4 h3 = *(const f32x4*)&tile[rg + 48][k4*4];
        #pragma unroll
        for (int ci = 0; ci < 4; ++ci) {
            const f32x4 wv = *(const f32x4*)(W2 + (size_t)(cg*4 + ci)*256 + k4*4);
            acc[0][ci] += wv.x*h0.x + wv.y*h0.y + wv.z*h0.z + wv.w*h0.w;
            acc[1][ci] += wv.x*h1.x + wv.y*h1.y + wv.z*h1.z + wv.w*h1.w;
            acc[2][ci] += wv.x*h2.x + wv.y*h2.y + wv.z*h2.z + wv.w*h2.w;
            acc[3][ci] += wv.x*h3.x + wv.y*h3.y + wv.z*h3.z + wv.w*h3.w;
        }
    }
    __syncthreads();

    #pragma unroll
    for (int ri = 0; ri < 4; ++ri) {
        f32x4 v;
        v.x = acc[ri][0] + b2v[0];
        v.y = acc[ri][1] + b2v[1];
        v.z = acc[ri][2] + b2v[2];
        v.w = acc[ri][3] + b2v[3];
        *(f32x4*)&tile[rg + 16*ri][cg*4] = v;
    }
    __syncthreads();

    const int wv_ = tid >> 6;
    const int l   = tid & 63;
    #pragma unroll
    for (int rr2 = 0; rr2 < 4; ++rr2) {
        const int r = wv_*4 + rr2;
        const float v0 = tile[r][l      ];
        const float v1 = tile[r][l +  64];
        const float v2 = tile[r][l + 128];
        const float v3 = tile[r][l + 192];
        float m = fmaxf(fmaxf(v0, v1), fmaxf(v2, v3));
        #pragma unroll
        for (int off = 32; off > 0; off >>= 1)
            m = fmaxf(m, __shfl_xor(m, off));
        const float e0 = expf(v0 - m), e1 = expf(v1 - m);
        const float e2 = expf(v2 - m), e3 = expf(v3 - m);
        float s = e0 + e1 + e2 + e3;
        #pragma unroll
        for (int off = 32; off > 0; off >>= 1)
            s += __shfl_xor(s, off);
        const float inv = 1.0f / s;
        float* op = io + (size_t)(m0 + r)*256;
        __builtin_nontemporal_store(e0*inv, op + l      );
        __builtin_nontemporal_store(e1*inv, op + l +  64);
        __builtin_nontemporal_store(e2*inv, op + l + 128);
        __builtin_nontemporal_store(e3*inv, op + l + 192);
    }
}

extern "C" void kernel_launch(void* const* d_in, const int* in_sizes, int n_in,
                              void* d_out, int out_size, void* d_ws, size_t ws_size,
                              hipStream_t stream) {
    // inputs: input, encoder_output, W_ih, b_ih, W_hh, b_hh, W2, b2
    // (input and W_ih are mathematically unused: x_part = 0 @ W_ih.T + b_ih)
    const float* enc  = (const float*)d_in[1];
    const float* b_ih = (const float*)d_in[3];
    const float* W_hh = (const float*)d_in[4];
    const float* b_hh = (const float*)d_in[5];
    const float* W2   = (const float*)d_in[6];
    const float* b2   = (const float*)d_in[7];
    float* outp = (float*)d_out;

    hipLaunchKernelGGL(rec_kernel, dim3(256), dim3(1024), 0, stream,
                       enc, b_ih, W_hh, b_hh, outp);
    hipLaunchKernelGGL(out_kernel, dim3(2048), dim3(1024), 0, stream,
                       W2, b2, outp);
}

// Round 18
// 2556.546 us; speedup vs baseline: 1.5882x; 1.5882x over previous
//
#include <hip/hip_runtime.h>
#include <math.h>
#include <stdint.h>

typedef float f32x4 __attribute__((ext_vector_type(4)));

__device__ __forceinline__ float sigm(float x) { return 1.0f/(1.0f+expf(-x)); }

// Sum across each 8-lane group via DIRECTION-PROOF DPP involutions:
// quad_perm xor1 (0xB1), quad_perm xor2 (0x4E) -> every lane holds its quad
// sum; row_half_mirror (0x141: i <-> 7-i within each 8-group) adds the other
// quad's sum. ALL 8 lanes end with the full 8-group sum. (Round-16 lesson:
// row_ror over a sub-group is rotation-direction-sensitive; XOR/mirror
// patterns are self-inverse -> direction-proof.)
__device__ __forceinline__ float red8(float v) {
    int t;
    t = __builtin_amdgcn_update_dpp(0, __float_as_int(v), 0xB1, 0xf, 0xf, false);
    v += __int_as_float(t);   // + lane^1 (quad_perm [1,0,3,2])
    t = __builtin_amdgcn_update_dpp(0, __float_as_int(v), 0x4E, 0xf, 0xf, false);
    v += __int_as_float(t);   // + lane^2 (quad_perm [2,3,0,1]) -> quad sums
    t = __builtin_amdgcn_update_dpp(0, __float_as_int(v), 0x141, 0xf, 0xf, false);
    v += __int_as_float(t);   // + mirrored lane (7-i in 8-group) -> 8-sum
    return v;
}

// ------------- Kernel 1: LSTM recurrence, all-direct K-split waves -------------
// Round-17 post-mortem: the 8x8 remap cut VALU as designed (VALUBusy 75->28%)
// but the per-lane CONSECUTIVE 16-float window made every load instruction
// stride-64B across lanes: 64 distinct 64B lines per instr for 1KB useful
// (4x TA transaction inflation) and h-reload banks collapsed to {0,16}
// (3.4e7 LDS conflicts) -> net 1.5x SLOWER. This round: INTERLEAVED layout.
// Lane's chunk i lives at half*128 + i*32 + kseg*4 (floats): per instruction
// 8 ksegs x 16B = 128B contiguous per row x 8 rows = 16 lines (optimal,
// round-15 coalescing); h-reload covers all 32 banks. Coverage: 8 ksegs x
// 4 chunks x 4 floats = all 128 floats of the half. Work mapping unchanged:
// 8 ksegs x 8 rows/wave, red8 over kseg groups, 16 phases x 64 gate-rows.
// 256 blocks x 1024 threads (4 waves/SIMD TLP hides L2), 2 batch rows/block.
// 2-deep pipeline (round-13: depth>2 null). ~48 VGPR. 2 lgkm barriers/step.
// Reference semantics: cell_state c0 CONSTANT (enc[:,-1,:]); carry = c_new.
__global__ __launch_bounds__(1024) void rec_kernel(
    const float* __restrict__ enc,   // (512, 64, 256)
    const float* __restrict__ b_ih,  // (1024)
    const float* __restrict__ W_hh,  // (1024, 256)
    const float* __restrict__ b_hh,  // (1024)
    float* __restrict__ hstage)      // (512, 256, 256) staging (= d_out)
{
    const int tid  = threadIdx.x;
    const int wv   = tid >> 6;          // wave 0..15
    const int lane = tid & 63;
    const int kseg = lane & 7;          // 8 K-segments (interleaved chunks)
    const int r8   = lane >> 3;         // 0..7: row within wave's group
    const int half = wv >> 3;           // K-half: 0 -> floats 0..127; 1 -> 128..255
    const int wg   = wv & 7;            // row group
    const int rloc = 8*wg + r8;         // row-in-phase (0..63) this lane computes
    const int b0   = blockIdx.x * 2;

    __shared__ float part[2][2][1024];  // [half][batch][gate-row] 16KB
    __shared__ float h_lds[2][256];     // 2KB

    // ---- pointwise identity: threads 0..511 = (pj, ph) ----
    const int pj = tid & 255;
    const int ph = (tid >> 8) & 1;
    float c0 = 0.f, pb0 = 0.f, pb1 = 0.f, pb2 = 0.f, pb3 = 0.f;
    float* __restrict__ outp = nullptr;
    if (tid < 512) {
        c0  = enc[(size_t)(b0 + ph)*16384 + 16128 + pj];
        pb0 = b_ih[      pj] + b_hh[      pj];
        pb1 = b_ih[256 + pj] + b_hh[256 + pj];
        pb2 = b_ih[512 + pj] + b_hh[512 + pj];
        pb3 = b_ih[768 + pj] + b_hh[768 + pj];
        outp = hstage + (size_t)(b0 + ph)*65536 + pj;
    }

    // per-lane W base: interleaved — chunk i at +i*32 floats
    // phase pm lives at + pm*64rows*256 = pm*16384 floats
    const float* __restrict__ wbase =
        W_hh + (size_t)rloc*256 + half*128 + kseg*4;

    #define LOADP(q0, q1, q2, q3, pm) do {                           \
        const float* wp_ = wbase + (size_t)(pm)*16384;               \
        q0 = *(const f32x4*)(wp_     );                              \
        q1 = *(const f32x4*)(wp_ + 32);                              \
        q2 = *(const f32x4*)(wp_ + 64);                              \
        q3 = *(const f32x4*)(wp_ + 96);                              \
    } while (0)

    #define COMPUTE(q0, q1, q2, q3, p) do {                          \
        f32x4 s0 = q0*h00; f32x4 s1 = q0*h10;                        \
        s0 += q1*h01;      s1 += q1*h11;                             \
        s0 += q2*h02;      s1 += q2*h12;                             \
        s0 += q3*h03;      s1 += q3*h13;                             \
        float a0 = (s0.x + s0.y) + (s0.z + s0.w);                    \
        float a1 = (s1.x + s1.y) + (s1.z + s1.w);                    \
        a0 = red8(a0); a1 = red8(a1);                                \
        if (kseg == 0) {                                             \
            const int grow_ = (p)*64 + rloc;                         \
            part[half][0][grow_] = a0;                               \
            part[half][1][grow_] = a1;                               \
        }                                                            \
    } while (0)

    // h windows: 16 floats per batch row (interleaved chunks), 32 VGPR
    f32x4 h00 = (f32x4)(0.f), h01 = (f32x4)(0.f),
          h02 = (f32x4)(0.f), h03 = (f32x4)(0.f);
    f32x4 h10 = (f32x4)(0.f), h11 = (f32x4)(0.f),
          h12 = (f32x4)(0.f), h13 = (f32x4)(0.f);

    f32x4 wA0, wA1, wA2, wA3, wB0, wB1, wB2, wB3;   // 2-deep pipeline (32 VGPR)

    // prologue: prime phases 0,1 (8 loads/wave in flight)
    LOADP(wA0, wA1, wA2, wA3, 0);
    LOADP(wB0, wB1, wB2, wB3, 1);

    for (int t = 0; t < 256; ++t) {
        #pragma unroll 1
        for (int pq = 0; pq < 8; ++pq) {
            const int p = pq*2;
            COMPUTE(wA0, wA1, wA2, wA3, p    );
            LOADP(wA0, wA1, wA2, wA3, (p + 2) & 15);
            COMPUTE(wB0, wB1, wB2, wB3, p + 1);
            LOADP(wB0, wB1, wB2, wB3, (p + 3) & 15);
        }   // (p+2/p+3 wrap to next step's phases: W identical every step)
        asm volatile("s_waitcnt lgkmcnt(0)" ::: "memory");
        __builtin_amdgcn_s_barrier();           // (1) all partials visible

        // ---- pointwise LSTM: threads 0..511, batch b0+ph, column pj ----
        if (tid < 512) {
            const float g0 = part[0][ph][      pj] + part[1][ph][      pj] + pb0;
            const float g1 = part[0][ph][256 + pj] + part[1][ph][256 + pj] + pb1;
            const float g2 = part[0][ph][512 + pj] + part[1][ph][512 + pj] + pb2;
            const float g3 = part[0][ph][768 + pj] + part[1][ph][768 + pj] + pb3;
            const float cn = sigm(g1)*c0 + sigm(g0)*tanhf(g2);
            const float hn = sigm(g3)*tanhf(cn);
            h_lds[ph][pj] = cn;                 // carry h_{t+1} = c_new
            __builtin_nontemporal_store(hn, outp + t*256);
        }
        asm volatile("s_waitcnt lgkmcnt(0)" ::: "memory");
        __builtin_amdgcn_s_barrier();           // (2) h ready

        // reload this wave's h window (interleaved: banks kseg*4..+3 ->
        // all 32 banks covered, 8-lane broadcast groups -> conflict-free)
        h00 = *(const f32x4*)&h_lds[0][half*128 + kseg*4     ];
        h01 = *(const f32x4*)&h_lds[0][half*128 + kseg*4 + 32];
        h02 = *(const f32x4*)&h_lds[0][half*128 + kseg*4 + 64];
        h03 = *(const f32x4*)&h_lds[0][half*128 + kseg*4 + 96];
        h10 = *(const f32x4*)&h_lds[1][half*128 + kseg*4     ];
        h11 = *(const f32x4*)&h_lds[1][half*128 + kseg*4 + 32];
        h12 = *(const f32x4*)&h_lds[1][half*128 + kseg*4 + 64];
        h13 = *(const f32x4*)&h_lds[1][half*128 + kseg*4 + 96];
    }
    #undef LOADP
    #undef COMPUTE
}

// ---------------- Kernel 2: logits + softmax, in place ----------------
// (unchanged — verified correct, ~106 us)
__global__ __launch_bounds__(1024) void out_kernel(
    const float* __restrict__ W2,    // (256, 256)
    const float* __restrict__ b2,    // (256)
    float* __restrict__ io)          // (131072, 256) h in, probs out
{
    const int tid = threadIdx.x;
    const int rg  = tid & 15;
    const int cg  = tid >> 4;        // 0..63
    const int m0  = blockIdx.x * 64;

    __shared__ float tile[64][260];

    #pragma unroll
    for (int i = 0; i < 4; ++i) {
        const int idx = tid + i*1024;     // 0..4095 float4 slots
        const int r   = idx >> 6;
        const int c4  = idx & 63;
        const f32x4 v = __builtin_nontemporal_load(
            (const f32x4*)(io + (size_t)(m0 + r)*256 + c4*4));
        *(f32x4*)&tile[r][c4*4] = v;
    }
    __syncthreads();

    float b2v[4];
    #pragma unroll
    for (int ci = 0; ci < 4; ++ci) b2v[ci] = b2[cg*4 + ci];

    float acc[4][4] = {};

    #pragma unroll 4
    for (int k4 = 0; k4 < 64; ++k4) {
        const f32x4 h0 = *(const f32x4*)&tile[rg     ][k4*4];
        const f32x4 h1 = *(const f32x4*)&tile[rg + 16][k4*4];
        const f32x4 h2 = *(const f32x4*)&tile[rg + 32][k4*4];
        const f32x4 h3 = *(const f32x4*)&tile[rg + 48][k4*4];
        #pragma unroll
        for (int ci = 0; ci < 4; ++ci) {
            const f32x4 wv = *(const f32x4*)(W2 + (size_t)(cg*4 + ci)*256 + k4*4);
            acc[0][ci] += wv.x*h0.x + wv.y*h0.y + wv.z*h0.z + wv.w*h0.w;
            acc[1][ci] += wv.x*h1.x + wv.y*h1.y + wv.z*h1.z + wv.w*h1.w;
            acc[2][ci] += wv.x*h2.x + wv.y*h2.y + wv.z*h2.z + wv.w*h2.w;
            acc[3][ci] += wv.x*h3.x + wv.y*h3.y + wv.z*h3.z + wv.w*h3.w;
        }
    }
    __syncthreads();

    #pragma unroll
    for (int ri = 0; ri < 4; ++ri) {
        f32x4 v;
        v.x = acc[ri][0] + b2v[0];
        v.y = acc[ri][1] + b2v[1];
        v.z = acc[ri][2] + b2v[2];
        v.w = acc[ri][3] + b2v[3];
        *(f32x4*)&tile[rg + 16*ri][cg*4] = v;
    }
    __syncthreads();

    const int wv_ = tid >> 6;
    const int l   = tid & 63;
    #pragma unroll
    for (int rr2 = 0; rr2 < 4; ++rr2) {
        const int r = wv_*4 + rr2;
        const float v0 = tile[r][l      ];
        const float v1 = tile[r][l +  64];
        const float v2 = tile[r][l + 128];
        const float v3 = tile[r][l + 192];
        float m = fmaxf(fmaxf(v0, v1), fmaxf(v2, v3));
        #pragma unroll
        for (int off = 32; off > 0; off >>= 1)
            m = fmaxf(m, __shfl_xor(m, off));
        const float e0 = expf(v0 - m), e1 = expf(v1 - m);
        const float e2 = expf(v2 - m), e3 = expf(v3 - m);
        float s = e0 + e1 + e2 + e3;
        #pragma unroll
        for (int off = 32; off > 0; off >>= 1)
            s += __shfl_xor(s, off);
        const float inv = 1.0f / s;
        float* op = io + (size_t)(m0 + r)*256;
        __builtin_nontemporal_store(e0*inv, op + l      );
        __builtin_nontemporal_store(e1*inv, op + l +  64);
        __builtin_nontemporal_store(e2*inv, op + l + 128);
        __builtin_nontemporal_store(e3*inv, op + l + 192);
    }
}

extern "C" void kernel_launch(void* const* d_in, const int* in_sizes, int n_in,
                              void* d_out, int out_size, void* d_ws, size_t ws_size,
                              hipStream_t stream) {
    // inputs: input, encoder_output, W_ih, b_ih, W_hh, b_hh, W2, b2
    // (input and W_ih are mathematically unused: x_part = 0 @ W_ih.T + b_ih)
    const float* enc  = (const float*)d_in[1];
    const float* b_ih = (const float*)d_in[3];
    const float* W_hh = (const float*)d_in[4];
    const float* b_hh = (const float*)d_in[5];
    const float* W2   = (const float*)d_in[6];
    const float* b2   = (const float*)d_in[7];
    float* outp = (float*)d_out;

    hipLaunchKernelGGL(rec_kernel, dim3(256), dim3(1024), 0, stream,
                       enc, b_ih, W_hh, b_hh, outp);
    hipLaunchKernelGGL(out_kernel, dim3(2048), dim3(1024), 0, stream,
                       W2, b2, outp);
}